// Round 1
// baseline (697.225 us; speedup 1.0000x reference)
//
#include <hip/hip_runtime.h>
#include <hip/hip_bf16.h>
#include <math.h>

#define B_   16
#define C_   512
#define D_   256
#define K_   16
#define RD_  128
#define H_   8
#define HD_  32
#define FFN_ 1024
#define M_   (B_ * C_)   // 8192 rows

// ---------------------------------------------------------------------------
// Generic fp32 GEMM: C[M,N] = A[M,Kd] @ W[N,Kd]^T + bias, optional exact GELU.
// 64x64 block tile, 256 threads, 4x4 micro-tile, K-tile 16.
// ---------------------------------------------------------------------------
__global__ __launch_bounds__(256) void gemm_bias_act(
    const float* __restrict__ A, const float* __restrict__ W,
    const float* __restrict__ bias, float* __restrict__ Cmat,
    int M, int N, int Kd, int act)
{
    __shared__ float As[16][65];
    __shared__ float Ws[16][65];
    const int tid = threadIdx.x;
    const int tx = tid & 15;        // 0..15 -> col group
    const int ty = tid >> 4;        // 0..15 -> row group
    const int bm = blockIdx.y * 64;
    const int bn = blockIdx.x * 64;

    float acc[4][4] = {};

    for (int k0 = 0; k0 < Kd; k0 += 16) {
        #pragma unroll
        for (int i = 0; i < 4; ++i) {
            int e  = tid + i * 256;      // 0..1023
            int r  = e >> 4;             // 0..63
            int kk = e & 15;             // 0..15
            As[kk][r] = A[(size_t)(bm + r) * Kd + k0 + kk];
            Ws[kk][r] = W[(size_t)(bn + r) * Kd + k0 + kk];
        }
        __syncthreads();
        #pragma unroll
        for (int kk = 0; kk < 16; ++kk) {
            float a[4], w[4];
            #pragma unroll
            for (int i = 0; i < 4; ++i) a[i] = As[kk][ty * 4 + i];
            #pragma unroll
            for (int j = 0; j < 4; ++j) w[j] = Ws[kk][tx * 4 + j];
            #pragma unroll
            for (int i = 0; i < 4; ++i)
                #pragma unroll
                for (int j = 0; j < 4; ++j)
                    acc[i][j] += a[i] * w[j];
        }
        __syncthreads();
    }

    #pragma unroll
    for (int i = 0; i < 4; ++i) {
        int m = bm + ty * 4 + i;
        #pragma unroll
        for (int j = 0; j < 4; ++j) {
            int n = bn + tx * 4 + j;
            float v = acc[i][j];
            if (bias) v += bias[n];
            if (act == 1) v = 0.5f * v * (1.0f + erff(v * 0.70710678118654752f));
            Cmat[(size_t)m * N + n] = v;
        }
    }
}

// ---------------------------------------------------------------------------
// Top-K selection. One block per (b,q) row: compute 512 logits (xq . xk),
// then 16 rounds of parallel argmax (lowest index wins ties).
// ---------------------------------------------------------------------------
__global__ __launch_bounds__(512) void topk_kernel(
    const float* __restrict__ xq, const float* __restrict__ xk,
    int* __restrict__ idx_out)
{
    const int b = blockIdx.y;
    const int q = blockIdx.x;
    const int t = threadIdx.x;    // 0..511, one per key position

    __shared__ float qv[RD_];
    __shared__ float sc[C_];
    __shared__ float rv[512];
    __shared__ int   ri[512];

    if (t < RD_) qv[t] = xq[((size_t)b * C_ + q) * RD_ + t];
    __syncthreads();

    const float* xkrow = &xk[((size_t)b * C_ + t) * RD_];
    float dot = 0.f;
    #pragma unroll 8
    for (int d = 0; d < RD_; ++d) dot += qv[d] * xkrow[d];
    sc[t] = dot;
    __syncthreads();

    for (int sel = 0; sel < K_; ++sel) {
        rv[t] = sc[t];
        ri[t] = t;
        __syncthreads();
        for (int s = 256; s > 0; s >>= 1) {
            if (t < s) {
                float v2 = rv[t + s];
                int   i2 = ri[t + s];
                if (v2 > rv[t] || (v2 == rv[t] && i2 < ri[t])) { rv[t] = v2; ri[t] = i2; }
            }
            __syncthreads();
        }
        if (t == 0) {
            int w = ri[0];
            idx_out[((size_t)b * C_ + q) * K_ + sel] = w;
            sc[w] = -INFINITY;
        }
        __syncthreads();
    }
}

// ---------------------------------------------------------------------------
// Attention over the K=16 gathered slots. One block (256 thr) per (b,q).
// qkv layout: row-major [M, 768]: cols 0..255 q, 256..511 k, 512..767 v.
// ---------------------------------------------------------------------------
__global__ __launch_bounds__(256) void attn_kernel(
    const float* __restrict__ qkv, const int* __restrict__ idx,
    float* __restrict__ ctx)
{
    const int b = blockIdx.y;
    const int q = blockIdx.x;
    const int t = threadIdx.x;   // 0..255

    __shared__ float qs[D_];
    __shared__ int   ii[K_];
    __shared__ float sc[H_][K_];
    __shared__ float aw[H_][K_];

    const size_t rowq = (size_t)b * C_ + q;
    qs[t] = qkv[rowq * 768 + t];
    if (t < K_) ii[t] = idx[rowq * K_ + t];
    __syncthreads();

    if (t < H_ * K_) {
        int h = t >> 4;          // head
        int k = t & 15;          // slot
        const size_t rowk = (size_t)b * C_ + ii[k];
        const float* kp = &qkv[rowk * 768 + 256 + h * HD_];
        float s = 0.f;
        #pragma unroll
        for (int d = 0; d < HD_; ++d) s += qs[h * HD_ + d] * kp[d];
        sc[h][k] = s * 0.17677669529663687f;   // 1/sqrt(32)
    }
    __syncthreads();

    if (t < H_) {
        float m = -INFINITY;
        for (int k = 0; k < K_; ++k) m = fmaxf(m, sc[t][k]);
        float ssum = 0.f;
        for (int k = 0; k < K_; ++k) { float e = expf(sc[t][k] - m); aw[t][k] = e; ssum += e; }
        float inv = 1.f / ssum;
        for (int k = 0; k < K_; ++k) aw[t][k] *= inv;
    }
    __syncthreads();

    {
        int h = t >> 5;          // 0..7
        float acc = 0.f;
        #pragma unroll
        for (int k = 0; k < K_; ++k) {
            const size_t rowv = (size_t)b * C_ + ii[k];
            acc += aw[h][k] * qkv[rowv * 768 + 512 + t];
        }
        ctx[rowq * D_ + t] = acc;
    }
}

// ---------------------------------------------------------------------------
// out[row] = LayerNorm(a[row] + res[row]) * g + beta.  One block per row.
// ---------------------------------------------------------------------------
__global__ __launch_bounds__(256) void add_ln_kernel(
    const float* __restrict__ a, const float* __restrict__ res,
    const float* __restrict__ g, const float* __restrict__ beta,
    float* __restrict__ out)
{
    const int row = blockIdx.x;
    const int t = threadIdx.x;
    __shared__ float red[256];

    float v = a[(size_t)row * D_ + t] + res[(size_t)row * D_ + t];

    red[t] = v;
    __syncthreads();
    for (int s = 128; s > 0; s >>= 1) { if (t < s) red[t] += red[t + s]; __syncthreads(); }
    float mean = red[0] * (1.0f / D_);
    __syncthreads();

    float dv = v - mean;
    red[t] = dv * dv;
    __syncthreads();
    for (int s = 128; s > 0; s >>= 1) { if (t < s) red[t] += red[t + s]; __syncthreads(); }
    float var = red[0] * (1.0f / D_);

    float r = rsqrtf(var + 1e-5f);
    out[(size_t)row * D_ + t] = dv * r * g[t] + beta[t];
}

// ---------------------------------------------------------------------------
extern "C" void kernel_launch(void* const* d_in, const int* in_sizes, int n_in,
                              void* d_out, int out_size, void* d_ws, size_t ws_size,
                              hipStream_t stream)
{
    const float* x      = (const float*)d_in[0];
    const float* wq_rec = (const float*)d_in[1];
    const float* wk_rec = (const float*)d_in[2];
    const float* in_w   = (const float*)d_in[3];
    const float* in_b   = (const float*)d_in[4];
    const float* out_w  = (const float*)d_in[5];
    const float* out_b  = (const float*)d_in[6];
    const float* ln1_g  = (const float*)d_in[7];
    const float* ln1_b  = (const float*)d_in[8];
    const float* w1     = (const float*)d_in[9];
    const float* b1     = (const float*)d_in[10];
    const float* w2     = (const float*)d_in[11];
    const float* b2     = (const float*)d_in[12];
    const float* ln2_g  = (const float*)d_in[13];
    const float* ln2_b  = (const float*)d_in[14];
    float* out = (float*)d_out;

    float* ws = (float*)d_ws;
    size_t off = 0;
    float* qkv  = ws + off;  off += (size_t)M_ * 768;   // 6.29M
    float* xq   = ws + off;  off += (size_t)M_ * RD_;   // 1.05M
    float* xk   = ws + off;  off += (size_t)M_ * RD_;   // 1.05M
    int*   idx  = (int*)(ws + off); off += (size_t)M_ * K_;  // 0.13M
    float* ctx  = ws + off;  off += (size_t)M_ * D_;    // 2.10M
    float* x1   = ws + off;  off += (size_t)M_ * D_;    // 2.10M
    float* hbuf = ws + off;  off += (size_t)M_ * FFN_;  // 8.39M
    float* ao   = ws + off;  off += (size_t)M_ * D_;    // attn_out / mlp-out (reused)

    dim3 blk(256);

    // 1) qkv = x @ in_proj_w^T + b   (8192 x 768 x 256)
    gemm_bias_act<<<dim3(768 / 64, M_ / 64), blk, 0, stream>>>(x, in_w, in_b, qkv, M_, 768, D_, 0);
    // 2) xq/xk recurrence projections (8192 x 128 x 256)
    gemm_bias_act<<<dim3(RD_ / 64, M_ / 64), blk, 0, stream>>>(x, wq_rec, nullptr, xq, M_, RD_, D_, 0);
    gemm_bias_act<<<dim3(RD_ / 64, M_ / 64), blk, 0, stream>>>(x, wk_rec, nullptr, xk, M_, RD_, D_, 0);
    // 3) per-row top-16
    topk_kernel<<<dim3(C_, B_), dim3(512), 0, stream>>>(xq, xk, idx);
    // 4) K=16 gathered attention
    attn_kernel<<<dim3(C_, B_), blk, 0, stream>>>(qkv, idx, ctx);
    // 5) out projection
    gemm_bias_act<<<dim3(D_ / 64, M_ / 64), blk, 0, stream>>>(ctx, out_w, out_b, ao, M_, D_, D_, 0);
    // 6) x1 = LN(attn_out + x)
    add_ln_kernel<<<dim3(M_), blk, 0, stream>>>(ao, x, ln1_g, ln1_b, x1);
    // 7) h = gelu(x1 @ w1^T + b1)   (8192 x 1024 x 256)
    gemm_bias_act<<<dim3(FFN_ / 64, M_ / 64), blk, 0, stream>>>(x1, w1, b1, hbuf, M_, FFN_, D_, 1);
    // 8) y = h @ w2^T + b2          (8192 x 256 x 1024)
    gemm_bias_act<<<dim3(D_ / 64, M_ / 64), blk, 0, stream>>>(hbuf, w2, b2, ao, M_, D_, FFN_, 0);
    // 9) out = LN(y + x1)
    add_ln_kernel<<<dim3(M_), blk, 0, stream>>>(ao, x1, ln2_g, ln2_b, out);
}

// Round 2
// 468.875 us; speedup vs baseline: 1.4870x; 1.4870x over previous
//
#include <hip/hip_runtime.h>
#include <hip/hip_bf16.h>
#include <math.h>

#define B_   16
#define C_   512
#define D_   256
#define K_   16
#define RD_  128
#define H_   8
#define HD_  32
#define FFN_ 1024
#define M_   (B_ * C_)   // 8192 rows

// ---------------------------------------------------------------------------
// Generic fp32 GEMM: C[M,N] = A[M,Kd] @ W[N,Kd]^T + bias, optional exact GELU.
// 64x64 block tile, 256 threads, 4x4 micro-tile, K-tile 16.
// ---------------------------------------------------------------------------
__global__ __launch_bounds__(256) void gemm_bias_act(
    const float* __restrict__ A, const float* __restrict__ W,
    const float* __restrict__ bias, float* __restrict__ Cmat,
    int M, int N, int Kd, int act)
{
    __shared__ float As[16][65];
    __shared__ float Ws[16][65];
    const int tid = threadIdx.x;
    const int tx = tid & 15;        // 0..15 -> col group
    const int ty = tid >> 4;        // 0..15 -> row group
    const int bm = blockIdx.y * 64;
    const int bn = blockIdx.x * 64;

    float acc[4][4] = {};

    for (int k0 = 0; k0 < Kd; k0 += 16) {
        #pragma unroll
        for (int i = 0; i < 4; ++i) {
            int e  = tid + i * 256;      // 0..1023
            int r  = e >> 4;             // 0..63
            int kk = e & 15;             // 0..15
            As[kk][r] = A[(size_t)(bm + r) * Kd + k0 + kk];
            Ws[kk][r] = W[(size_t)(bn + r) * Kd + k0 + kk];
        }
        __syncthreads();
        #pragma unroll
        for (int kk = 0; kk < 16; ++kk) {
            float a[4], w[4];
            #pragma unroll
            for (int i = 0; i < 4; ++i) a[i] = As[kk][ty * 4 + i];
            #pragma unroll
            for (int j = 0; j < 4; ++j) w[j] = Ws[kk][tx * 4 + j];
            #pragma unroll
            for (int i = 0; i < 4; ++i)
                #pragma unroll
                for (int j = 0; j < 4; ++j)
                    acc[i][j] += a[i] * w[j];
        }
        __syncthreads();
    }

    #pragma unroll
    for (int i = 0; i < 4; ++i) {
        int m = bm + ty * 4 + i;
        #pragma unroll
        for (int j = 0; j < 4; ++j) {
            int n = bn + tx * 4 + j;
            float v = acc[i][j];
            if (bias) v += bias[n];
            if (act == 1) v = 0.5f * v * (1.0f + erff(v * 0.70710678118654752f));
            Cmat[(size_t)m * N + n] = v;
        }
    }
}

// ---------------------------------------------------------------------------
// Batched logits GEMM: logits[b, q, c] = xq[b,q,:] . xk[b,c,:]  (Kd = 128)
// Per batch: 512x512x128. 64x64 tile, same micro-structure as gemm_bias_act.
// (1/TEMP scaling dropped: monotone, does not affect top-k selection.)
// ---------------------------------------------------------------------------
__global__ __launch_bounds__(256) void logits_gemm(
    const float* __restrict__ xq, const float* __restrict__ xk,
    float* __restrict__ out)
{
    __shared__ float As[16][65];
    __shared__ float Ws[16][65];
    const int tid = threadIdx.x;
    const int tx = tid & 15;
    const int ty = tid >> 4;
    const int bm = blockIdx.y * 64;
    const int bn = blockIdx.x * 64;
    const int b  = blockIdx.z;

    const float* A = xq + (size_t)b * C_ * RD_;
    const float* W = xk + (size_t)b * C_ * RD_;
    float* Cmat    = out + (size_t)b * C_ * C_;

    float acc[4][4] = {};

    for (int k0 = 0; k0 < RD_; k0 += 16) {
        #pragma unroll
        for (int i = 0; i < 4; ++i) {
            int e  = tid + i * 256;
            int r  = e >> 4;
            int kk = e & 15;
            As[kk][r] = A[(size_t)(bm + r) * RD_ + k0 + kk];
            Ws[kk][r] = W[(size_t)(bn + r) * RD_ + k0 + kk];
        }
        __syncthreads();
        #pragma unroll
        for (int kk = 0; kk < 16; ++kk) {
            float a[4], w[4];
            #pragma unroll
            for (int i = 0; i < 4; ++i) a[i] = As[kk][ty * 4 + i];
            #pragma unroll
            for (int j = 0; j < 4; ++j) w[j] = Ws[kk][tx * 4 + j];
            #pragma unroll
            for (int i = 0; i < 4; ++i)
                #pragma unroll
                for (int j = 0; j < 4; ++j)
                    acc[i][j] += a[i] * w[j];
        }
        __syncthreads();
    }

    #pragma unroll
    for (int i = 0; i < 4; ++i)
        #pragma unroll
        for (int j = 0; j < 4; ++j)
            Cmat[(size_t)(bm + ty * 4 + i) * C_ + bn + tx * 4 + j] = acc[i][j];
}

// ---------------------------------------------------------------------------
// Top-16 of each 512-row, one WAVE per row, zero barriers.
// Keys: (ordered-float-bits << 9) | (511 - pos)  -> max key == top value,
// lowest index on ties (matches jax.lax.top_k). 16 rounds of in-register
// max (8 slots) + 6-step shuffle butterfly.
// ---------------------------------------------------------------------------
__global__ __launch_bounds__(256) void topk_select(
    const float* __restrict__ logits, int* __restrict__ idx_out)
{
    const int wave = threadIdx.x >> 6;
    const int lane = threadIdx.x & 63;
    const int row  = blockIdx.x * 4 + wave;
    const float* lrow = logits + (size_t)row * C_;

    unsigned long long key[8];
    #pragma unroll
    for (int j = 0; j < 8; ++j) {
        int pos = lane * 8 + j;
        unsigned u = __float_as_uint(lrow[pos]);
        u = (u & 0x80000000u) ? ~u : (u | 0x80000000u);
        key[j] = (((unsigned long long)u) << 9) | (unsigned)(511 - pos);
    }

    #pragma unroll
    for (int sel = 0; sel < K_; ++sel) {
        unsigned long long best = key[0];
        #pragma unroll
        for (int j = 1; j < 8; ++j) best = key[j] > best ? key[j] : best;
        #pragma unroll
        for (int s = 1; s < 64; s <<= 1) {
            unsigned long long o = __shfl_xor(best, s, 64);
            best = o > best ? o : best;
        }
        int pos = 511 - (int)(best & 511ull);
        if (lane == 0) idx_out[(size_t)row * K_ + sel] = pos;
        if ((pos >> 3) == lane) key[pos & 7] = 0ull;
    }
}

// ---------------------------------------------------------------------------
// Attention over the K=16 gathered slots. One block (256 thr) per (b,q).
// qkv layout: row-major [M, 768]: cols 0..255 q, 256..511 k, 512..767 v.
// ---------------------------------------------------------------------------
__global__ __launch_bounds__(256) void attn_kernel(
    const float* __restrict__ qkv, const int* __restrict__ idx,
    float* __restrict__ ctx)
{
    const int b = blockIdx.y;
    const int q = blockIdx.x;
    const int t = threadIdx.x;   // 0..255

    __shared__ float qs[D_];
    __shared__ int   ii[K_];
    __shared__ float sc[H_][K_];
    __shared__ float aw[H_][K_];

    const size_t rowq = (size_t)b * C_ + q;
    qs[t] = qkv[rowq * 768 + t];
    if (t < K_) ii[t] = idx[rowq * K_ + t];
    __syncthreads();

    if (t < H_ * K_) {
        int h = t >> 4;          // head
        int k = t & 15;          // slot
        const size_t rowk = (size_t)b * C_ + ii[k];
        const float* kp = &qkv[rowk * 768 + 256 + h * HD_];
        float s = 0.f;
        #pragma unroll
        for (int d = 0; d < HD_; ++d) s += qs[h * HD_ + d] * kp[d];
        sc[h][k] = s * 0.17677669529663687f;   // 1/sqrt(32)
    }
    __syncthreads();

    if (t < H_) {
        float m = -INFINITY;
        for (int k = 0; k < K_; ++k) m = fmaxf(m, sc[t][k]);
        float ssum = 0.f;
        for (int k = 0; k < K_; ++k) { float e = expf(sc[t][k] - m); aw[t][k] = e; ssum += e; }
        float inv = 1.f / ssum;
        for (int k = 0; k < K_; ++k) aw[t][k] *= inv;
    }
    __syncthreads();

    {
        int h = t >> 5;          // 0..7
        float acc = 0.f;
        #pragma unroll
        for (int k = 0; k < K_; ++k) {
            const size_t rowv = (size_t)b * C_ + ii[k];
            acc += aw[h][k] * qkv[rowv * 768 + 512 + t];
        }
        ctx[rowq * D_ + t] = acc;
    }
}

// ---------------------------------------------------------------------------
// out[row] = LayerNorm(a[row] + res[row]) * g + beta.  One block per row.
// ---------------------------------------------------------------------------
__global__ __launch_bounds__(256) void add_ln_kernel(
    const float* __restrict__ a, const float* __restrict__ res,
    const float* __restrict__ g, const float* __restrict__ beta,
    float* __restrict__ out)
{
    const int row = blockIdx.x;
    const int t = threadIdx.x;
    __shared__ float red[256];

    float v = a[(size_t)row * D_ + t] + res[(size_t)row * D_ + t];

    red[t] = v;
    __syncthreads();
    for (int s = 128; s > 0; s >>= 1) { if (t < s) red[t] += red[t + s]; __syncthreads(); }
    float mean = red[0] * (1.0f / D_);
    __syncthreads();

    float dv = v - mean;
    red[t] = dv * dv;
    __syncthreads();
    for (int s = 128; s > 0; s >>= 1) { if (t < s) red[t] += red[t + s]; __syncthreads(); }
    float var = red[0] * (1.0f / D_);

    float r = rsqrtf(var + 1e-5f);
    out[(size_t)row * D_ + t] = dv * r * g[t] + beta[t];
}

// ---------------------------------------------------------------------------
extern "C" void kernel_launch(void* const* d_in, const int* in_sizes, int n_in,
                              void* d_out, int out_size, void* d_ws, size_t ws_size,
                              hipStream_t stream)
{
    const float* x      = (const float*)d_in[0];
    const float* wq_rec = (const float*)d_in[1];
    const float* wk_rec = (const float*)d_in[2];
    const float* in_w   = (const float*)d_in[3];
    const float* in_b   = (const float*)d_in[4];
    const float* out_w  = (const float*)d_in[5];
    const float* out_b  = (const float*)d_in[6];
    const float* ln1_g  = (const float*)d_in[7];
    const float* ln1_b  = (const float*)d_in[8];
    const float* w1     = (const float*)d_in[9];
    const float* b1     = (const float*)d_in[10];
    const float* w2     = (const float*)d_in[11];
    const float* b2     = (const float*)d_in[12];
    const float* ln2_g  = (const float*)d_in[13];
    const float* ln2_b  = (const float*)d_in[14];
    float* out = (float*)d_out;

    float* ws = (float*)d_ws;
    size_t off = 0;
    float* qkv  = ws + off;  off += (size_t)M_ * 768;   // 6.29M
    float* xq   = ws + off;  off += (size_t)M_ * RD_;   // 1.05M
    float* xk   = ws + off;  off += (size_t)M_ * RD_;   // 1.05M
    int*   idx  = (int*)(ws + off); off += (size_t)M_ * K_;  // 0.13M
    float* ctx  = ws + off;  off += (size_t)M_ * D_;    // 2.10M
    float* x1   = ws + off;  off += (size_t)M_ * D_;    // 2.10M
    float* hbuf = ws + off;  off += (size_t)M_ * FFN_;  // 8.39M
    float* ao   = ws + off;  off += (size_t)M_ * D_;    // attn_out / mlp-out (reused)

    // logits [B, C, C] = 4.2M floats; aliases hbuf (hbuf only live from step 7).
    float* logits = hbuf;

    dim3 blk(256);

    // 1) qkv = x @ in_proj_w^T + b   (8192 x 768 x 256)
    gemm_bias_act<<<dim3(768 / 64, M_ / 64), blk, 0, stream>>>(x, in_w, in_b, qkv, M_, 768, D_, 0);
    // 2) xq/xk recurrence projections (8192 x 128 x 256)
    gemm_bias_act<<<dim3(RD_ / 64, M_ / 64), blk, 0, stream>>>(x, wq_rec, nullptr, xq, M_, RD_, D_, 0);
    gemm_bias_act<<<dim3(RD_ / 64, M_ / 64), blk, 0, stream>>>(x, wk_rec, nullptr, xk, M_, RD_, D_, 0);
    // 3a) logits = xq @ xk^T per batch (16 x 512x512x128)
    logits_gemm<<<dim3(C_ / 64, C_ / 64, B_), blk, 0, stream>>>(xq, xk, logits);
    // 3b) per-row top-16, one wave per row
    topk_select<<<dim3(M_ / 4), blk, 0, stream>>>(logits, idx);
    // 4) K=16 gathered attention
    attn_kernel<<<dim3(C_, B_), blk, 0, stream>>>(qkv, idx, ctx);
    // 5) out projection
    gemm_bias_act<<<dim3(D_ / 64, M_ / 64), blk, 0, stream>>>(ctx, out_w, out_b, ao, M_, D_, D_, 0);
    // 6) x1 = LN(attn_out + x)
    add_ln_kernel<<<dim3(M_), blk, 0, stream>>>(ao, x, ln1_g, ln1_b, x1);
    // 7) h = gelu(x1 @ w1^T + b1)   (8192 x 1024 x 256)
    gemm_bias_act<<<dim3(FFN_ / 64, M_ / 64), blk, 0, stream>>>(x1, w1, b1, hbuf, M_, FFN_, D_, 1);
    // 8) y = h @ w2^T + b2          (8192 x 256 x 1024)
    gemm_bias_act<<<dim3(D_ / 64, M_ / 64), blk, 0, stream>>>(hbuf, w2, b2, ao, M_, D_, FFN_, 0);
    // 9) out = LN(y + x1)
    add_ln_kernel<<<dim3(M_), blk, 0, stream>>>(ao, x1, ln2_g, ln2_b, out);
}

// Round 3
// 233.169 us; speedup vs baseline: 2.9902x; 2.0109x over previous
//
#include <hip/hip_runtime.h>
#include <hip/hip_bf16.h>
#include <math.h>

#define B_   16
#define C_   512
#define D_   256
#define K_   16
#define RD_  128
#define H_   8
#define HD_  32
#define FFN_ 1024
#define M_   (B_ * C_)   // 8192 rows

typedef __attribute__((ext_vector_type(8))) short bf16x8;
typedef __attribute__((ext_vector_type(4))) float f32x4;

static __device__ __forceinline__ short f2bf(float v) {
    __hip_bfloat16 h = __float2bfloat16(v);
    return *(short*)&h;
}

// ---------------------------------------------------------------------------
// fp32 -> bf16 convert, 8 elements per thread.
// ---------------------------------------------------------------------------
__global__ __launch_bounds__(256) void convert_bf16_kernel(
    const float* __restrict__ src, short* __restrict__ dst, int n8)
{
    int i = blockIdx.x * 256 + threadIdx.x;
    if (i >= n8) return;
    const float4* s = (const float4*)src + (size_t)i * 2;
    float4 v0 = s[0], v1 = s[1];
    short r[8];
    r[0]=f2bf(v0.x); r[1]=f2bf(v0.y); r[2]=f2bf(v0.z); r[3]=f2bf(v0.w);
    r[4]=f2bf(v1.x); r[5]=f2bf(v1.y); r[6]=f2bf(v1.z); r[7]=f2bf(v1.w);
    *(bf16x8*)(dst + (size_t)i * 8) = *(bf16x8*)r;
}

// ---------------------------------------------------------------------------
// bf16 MFMA GEMM: C[M,N] = A[M,Kd] @ W[N,Kd]^T + bias (+exact GELU).
// 128x128 tile, BK=32, 256 threads = 4 waves, each wave 64x64 (4x4 frags of
// 16x16x32). fp32 accumulation. OUT_BF16 selects output dtype.
// ---------------------------------------------------------------------------
template<int OUT_BF16, int ACT>
__global__ __launch_bounds__(256) void gemm_mfma(
    const short* __restrict__ A, const short* __restrict__ W,
    const float* __restrict__ bias, void* __restrict__ Cout,
    int M, int N, int Kd)
{
    __shared__ short As[128 * 32];
    __shared__ short Bs[128 * 32];
    const int tid  = threadIdx.x;
    const int wave = tid >> 6;
    const int lane = tid & 63;
    const int bm = blockIdx.y * 128;
    const int bn = blockIdx.x * 128;
    const int wr = (wave >> 1) * 64;   // wave's row offset in tile
    const int wc = (wave & 1) * 64;    // wave's col offset in tile

    const int fr = lane & 15;          // fragment row/col within 16
    const int fk = (lane >> 4) * 8;    // fragment k offset

    // staging: 512 chunks of 8 bf16; thread t does chunks t and t+256
    const int r0 = tid >> 2,           ch0 = (tid & 3) * 8;
    const int r1 = (tid + 256) >> 2,   ch1 = (tid & 3) * 8;  // (tid+256)&3 == tid&3

    f32x4 acc[4][4];
    #pragma unroll
    for (int i = 0; i < 4; ++i)
        #pragma unroll
        for (int j = 0; j < 4; ++j)
            acc[i][j] = (f32x4){0.f, 0.f, 0.f, 0.f};

    for (int k0 = 0; k0 < Kd; k0 += 32) {
        *(bf16x8*)&As[tid * 8]         = *(const bf16x8*)&A[(size_t)(bm + r0) * Kd + k0 + ch0];
        *(bf16x8*)&As[(tid + 256) * 8] = *(const bf16x8*)&A[(size_t)(bm + r1) * Kd + k0 + ch1];
        *(bf16x8*)&Bs[tid * 8]         = *(const bf16x8*)&W[(size_t)(bn + r0) * Kd + k0 + ch0];
        *(bf16x8*)&Bs[(tid + 256) * 8] = *(const bf16x8*)&W[(size_t)(bn + r1) * Kd + k0 + ch1];
        __syncthreads();
        bf16x8 af[4], bfr[4];
        #pragma unroll
        for (int i = 0; i < 4; ++i) af[i]  = *(bf16x8*)&As[(wr + i * 16 + fr) * 32 + fk];
        #pragma unroll
        for (int j = 0; j < 4; ++j) bfr[j] = *(bf16x8*)&Bs[(wc + j * 16 + fr) * 32 + fk];
        #pragma unroll
        for (int i = 0; i < 4; ++i)
            #pragma unroll
            for (int j = 0; j < 4; ++j)
                acc[i][j] = __builtin_amdgcn_mfma_f32_16x16x32_bf16(af[i], bfr[j], acc[i][j], 0, 0, 0);
        __syncthreads();
    }

    // epilogue: D mapping col = lane&15, row = (lane>>4)*4 + reg
    const int rowbase = (lane >> 4) * 4;
    #pragma unroll
    for (int i = 0; i < 4; ++i) {
        #pragma unroll
        for (int j = 0; j < 4; ++j) {
            const int n = bn + wc + j * 16 + fr;
            const float bn_v = bias ? bias[n] : 0.f;
            #pragma unroll
            for (int r = 0; r < 4; ++r) {
                const int m = bm + wr + i * 16 + rowbase + r;
                float v = acc[i][j][r] + bn_v;
                if (ACT) v = 0.5f * v * (1.0f + erff(v * 0.70710678118654752f));
                if (OUT_BF16) ((short*)Cout)[(size_t)m * N + n] = f2bf(v);
                else          ((float*)Cout)[(size_t)m * N + n] = v;
            }
        }
    }
}

// ---------------------------------------------------------------------------
// fp32 GEMM (kept for the exact top-k path): C = A @ W^T.
// ---------------------------------------------------------------------------
__global__ __launch_bounds__(256) void gemm_bias_act(
    const float* __restrict__ A, const float* __restrict__ W,
    const float* __restrict__ bias, float* __restrict__ Cmat,
    int M, int N, int Kd, int act)
{
    __shared__ float As[16][65];
    __shared__ float Ws[16][65];
    const int tid = threadIdx.x;
    const int tx = tid & 15;
    const int ty = tid >> 4;
    const int bm = blockIdx.y * 64;
    const int bn = blockIdx.x * 64;

    float acc[4][4] = {};

    for (int k0 = 0; k0 < Kd; k0 += 16) {
        #pragma unroll
        for (int i = 0; i < 4; ++i) {
            int e  = tid + i * 256;
            int r  = e >> 4;
            int kk = e & 15;
            As[kk][r] = A[(size_t)(bm + r) * Kd + k0 + kk];
            Ws[kk][r] = W[(size_t)(bn + r) * Kd + k0 + kk];
        }
        __syncthreads();
        #pragma unroll
        for (int kk = 0; kk < 16; ++kk) {
            float a[4], w[4];
            #pragma unroll
            for (int i = 0; i < 4; ++i) a[i] = As[kk][ty * 4 + i];
            #pragma unroll
            for (int j = 0; j < 4; ++j) w[j] = Ws[kk][tx * 4 + j];
            #pragma unroll
            for (int i = 0; i < 4; ++i)
                #pragma unroll
                for (int j = 0; j < 4; ++j)
                    acc[i][j] += a[i] * w[j];
        }
        __syncthreads();
    }

    #pragma unroll
    for (int i = 0; i < 4; ++i) {
        int m = bm + ty * 4 + i;
        #pragma unroll
        for (int j = 0; j < 4; ++j) {
            int n = bn + tx * 4 + j;
            float v = acc[i][j];
            if (bias) v += bias[n];
            Cmat[(size_t)m * N + n] = v;
        }
    }
}

// ---------------------------------------------------------------------------
// Batched logits GEMM (fp32, exact): logits[b,q,c] = xq[b,q,:] . xk[b,c,:]
// ---------------------------------------------------------------------------
__global__ __launch_bounds__(256) void logits_gemm(
    const float* __restrict__ xq, const float* __restrict__ xk,
    float* __restrict__ out)
{
    __shared__ float As[16][65];
    __shared__ float Ws[16][65];
    const int tid = threadIdx.x;
    const int tx = tid & 15;
    const int ty = tid >> 4;
    const int bm = blockIdx.y * 64;
    const int bn = blockIdx.x * 64;
    const int b  = blockIdx.z;

    const float* A = xq + (size_t)b * C_ * RD_;
    const float* W = xk + (size_t)b * C_ * RD_;
    float* Cmat    = out + (size_t)b * C_ * C_;

    float acc[4][4] = {};

    for (int k0 = 0; k0 < RD_; k0 += 16) {
        #pragma unroll
        for (int i = 0; i < 4; ++i) {
            int e  = tid + i * 256;
            int r  = e >> 4;
            int kk = e & 15;
            As[kk][r] = A[(size_t)(bm + r) * RD_ + k0 + kk];
            Ws[kk][r] = W[(size_t)(bn + r) * RD_ + k0 + kk];
        }
        __syncthreads();
        #pragma unroll
        for (int kk = 0; kk < 16; ++kk) {
            float a[4], w[4];
            #pragma unroll
            for (int i = 0; i < 4; ++i) a[i] = As[kk][ty * 4 + i];
            #pragma unroll
            for (int j = 0; j < 4; ++j) w[j] = Ws[kk][tx * 4 + j];
            #pragma unroll
            for (int i = 0; i < 4; ++i)
                #pragma unroll
                for (int j = 0; j < 4; ++j)
                    acc[i][j] += a[i] * w[j];
        }
        __syncthreads();
    }

    #pragma unroll
    for (int i = 0; i < 4; ++i)
        #pragma unroll
        for (int j = 0; j < 4; ++j)
            Cmat[(size_t)(bm + ty * 4 + i) * C_ + bn + tx * 4 + j] = acc[i][j];
}

// ---------------------------------------------------------------------------
// Top-16 per 512-row, one wave per row, zero barriers.
// ---------------------------------------------------------------------------
__global__ __launch_bounds__(256) void topk_select(
    const float* __restrict__ logits, int* __restrict__ idx_out)
{
    const int wave = threadIdx.x >> 6;
    const int lane = threadIdx.x & 63;
    const int row  = blockIdx.x * 4 + wave;
    const float* lrow = logits + (size_t)row * C_;

    unsigned long long key[8];
    #pragma unroll
    for (int j = 0; j < 8; ++j) {
        int pos = lane * 8 + j;
        unsigned u = __float_as_uint(lrow[pos]);
        u = (u & 0x80000000u) ? ~u : (u | 0x80000000u);
        key[j] = (((unsigned long long)u) << 9) | (unsigned)(511 - pos);
    }

    #pragma unroll
    for (int sel = 0; sel < K_; ++sel) {
        unsigned long long best = key[0];
        #pragma unroll
        for (int j = 1; j < 8; ++j) best = key[j] > best ? key[j] : best;
        #pragma unroll
        for (int s = 1; s < 64; s <<= 1) {
            unsigned long long o = __shfl_xor(best, s, 64);
            best = o > best ? o : best;
        }
        int pos = 511 - (int)(best & 511ull);
        if (lane == 0) idx_out[(size_t)row * K_ + sel] = pos;
        if ((pos >> 3) == lane) key[pos & 7] = 0ull;
    }
}

// ---------------------------------------------------------------------------
// K=16 gathered attention; writes ctx as bf16. One block (256 thr) per (b,q).
// ---------------------------------------------------------------------------
__global__ __launch_bounds__(256) void attn_kernel(
    const float* __restrict__ qkv, const int* __restrict__ idx,
    short* __restrict__ ctxbf)
{
    const int b = blockIdx.y;
    const int q = blockIdx.x;
    const int t = threadIdx.x;   // 0..255

    __shared__ float qs[D_];
    __shared__ int   ii[K_];
    __shared__ float sc[H_][K_];
    __shared__ float aw[H_][K_];

    const size_t rowq = (size_t)b * C_ + q;
    qs[t] = qkv[rowq * 768 + t];
    if (t < K_) ii[t] = idx[rowq * K_ + t];
    __syncthreads();

    if (t < H_ * K_) {
        int h = t >> 4;
        int k = t & 15;
        const size_t rowk = (size_t)b * C_ + ii[k];
        const float* kp = &qkv[rowk * 768 + 256 + h * HD_];
        float s = 0.f;
        #pragma unroll
        for (int d = 0; d < HD_; ++d) s += qs[h * HD_ + d] * kp[d];
        sc[h][k] = s * 0.17677669529663687f;
    }
    __syncthreads();

    if (t < H_) {
        float m = -INFINITY;
        for (int k = 0; k < K_; ++k) m = fmaxf(m, sc[t][k]);
        float ssum = 0.f;
        for (int k = 0; k < K_; ++k) { float e = expf(sc[t][k] - m); aw[t][k] = e; ssum += e; }
        float inv = 1.f / ssum;
        for (int k = 0; k < K_; ++k) aw[t][k] *= inv;
    }
    __syncthreads();

    {
        int h = t >> 5;
        float acc = 0.f;
        #pragma unroll
        for (int k = 0; k < K_; ++k) {
            const size_t rowv = (size_t)b * C_ + ii[k];
            acc += aw[h][k] * qkv[rowv * 768 + 512 + t];
        }
        ctxbf[rowq * D_ + t] = f2bf(acc);
    }
}

// ---------------------------------------------------------------------------
// out = LN(a + res); optionally also bf16 copy. One block per row.
// ---------------------------------------------------------------------------
template<int WBF>
__global__ __launch_bounds__(256) void add_ln_kernel(
    const float* __restrict__ a, const float* __restrict__ res,
    const float* __restrict__ g, const float* __restrict__ beta,
    float* __restrict__ out, short* __restrict__ outbf)
{
    const int row = blockIdx.x;
    const int t = threadIdx.x;
    __shared__ float red[256];

    float v = a[(size_t)row * D_ + t] + res[(size_t)row * D_ + t];

    red[t] = v;
    __syncthreads();
    for (int s = 128; s > 0; s >>= 1) { if (t < s) red[t] += red[t + s]; __syncthreads(); }
    float mean = red[0] * (1.0f / D_);
    __syncthreads();

    float dv = v - mean;
    red[t] = dv * dv;
    __syncthreads();
    for (int s = 128; s > 0; s >>= 1) { if (t < s) red[t] += red[t + s]; __syncthreads(); }
    float var = red[0] * (1.0f / D_);

    float r = rsqrtf(var + 1e-5f);
    float o = dv * r * g[t] + beta[t];
    out[(size_t)row * D_ + t] = o;
    if (WBF) outbf[(size_t)row * D_ + t] = f2bf(o);
}

// ---------------------------------------------------------------------------
extern "C" void kernel_launch(void* const* d_in, const int* in_sizes, int n_in,
                              void* d_out, int out_size, void* d_ws, size_t ws_size,
                              hipStream_t stream)
{
    const float* x      = (const float*)d_in[0];
    const float* wq_rec = (const float*)d_in[1];
    const float* wk_rec = (const float*)d_in[2];
    const float* in_w   = (const float*)d_in[3];
    const float* in_b   = (const float*)d_in[4];
    const float* out_w  = (const float*)d_in[5];
    const float* out_b  = (const float*)d_in[6];
    const float* ln1_g  = (const float*)d_in[7];
    const float* ln1_b  = (const float*)d_in[8];
    const float* w1     = (const float*)d_in[9];
    const float* b1     = (const float*)d_in[10];
    const float* w2     = (const float*)d_in[11];
    const float* b2     = (const float*)d_in[12];
    const float* ln2_g  = (const float*)d_in[13];
    const float* ln2_b  = (const float*)d_in[14];
    float* out = (float*)d_out;

    // ---- workspace layout (floats) ----
    float* ws = (float*)d_ws;
    float* qkv   = ws;                              // M*768 f
    float* xq    = qkv + (size_t)M_ * 768;          // M*128 f
    float* xk    = xq  + (size_t)M_ * RD_;          // M*128 f
    int*   idx   = (int*)(xk + (size_t)M_ * RD_);   // M*16 i32
    float* x1    = (float*)(idx + (size_t)M_ * K_); // M*256 f
    float* ao    = x1 + (size_t)M_ * D_;            // M*256 f
    float* U     = ao + (size_t)M_ * D_;            // union region, 3*M*256 f worth
    // union members (sequenced lifetimes):
    float* logits = U;                                  // M*512 f      (topk phase)
    short* ctxbf  = (short*)U;                          // M*256 bf16   (attn->outproj)
    short* x1bf   = (short*)U + (size_t)M_ * D_;        // M*256 bf16   (ln1->mlp1)
    short* hbf    = (short*)U + (size_t)2 * M_ * D_;    // M*1024 bf16  (mlp1->mlp2)
    float* afterU = U + (size_t)3 * M_ * D_;            // == U + 6*M*D_ shorts
    short* xbf    = (short*)afterU;                     // M*256 bf16
    short* inwbf  = xbf   + (size_t)M_ * D_;            // 768*256
    short* outwbf = inwbf + (size_t)768 * D_;           // 256*256
    short* w1bf   = outwbf + (size_t)D_ * D_;           // 1024*256
    short* w2bf   = w1bf  + (size_t)FFN_ * D_;          // 256*1024

    dim3 blk(256);

    // 0) bf16 conversions
    convert_bf16_kernel<<<dim3((M_ * D_ / 8 + 255) / 256), blk, 0, stream>>>(x, xbf, M_ * D_ / 8);
    convert_bf16_kernel<<<dim3((768 * D_ / 8 + 255) / 256), blk, 0, stream>>>(in_w, inwbf, 768 * D_ / 8);
    convert_bf16_kernel<<<dim3((D_ * D_ / 8 + 255) / 256), blk, 0, stream>>>(out_w, outwbf, D_ * D_ / 8);
    convert_bf16_kernel<<<dim3((FFN_ * D_ / 8 + 255) / 256), blk, 0, stream>>>(w1, w1bf, FFN_ * D_ / 8);
    convert_bf16_kernel<<<dim3((D_ * FFN_ / 8 + 255) / 256), blk, 0, stream>>>(w2, w2bf, D_ * FFN_ / 8);

    // 1) qkv = x @ in_proj_w^T + b  (MFMA, fp32 out)
    gemm_mfma<0, 0><<<dim3(768 / 128, M_ / 128), blk, 0, stream>>>(xbf, inwbf, in_b, qkv, M_, 768, D_);
    // 2) xq/xk recurrence projections (fp32 exact — feeds top-k)
    gemm_bias_act<<<dim3(RD_ / 64, M_ / 64), blk, 0, stream>>>(x, wq_rec, nullptr, xq, M_, RD_, D_, 0);
    gemm_bias_act<<<dim3(RD_ / 64, M_ / 64), blk, 0, stream>>>(x, wk_rec, nullptr, xk, M_, RD_, D_, 0);
    // 3) logits + top-16 (fp32 exact)
    logits_gemm<<<dim3(C_ / 64, C_ / 64, B_), blk, 0, stream>>>(xq, xk, logits);
    topk_select<<<dim3(M_ / 4), blk, 0, stream>>>(logits, idx);
    // 4) gathered attention -> ctx (bf16)
    attn_kernel<<<dim3(C_, B_), blk, 0, stream>>>(qkv, idx, ctxbf);
    // 5) out projection (MFMA, fp32 out)
    gemm_mfma<0, 0><<<dim3(D_ / 128, M_ / 128), blk, 0, stream>>>(ctxbf, outwbf, out_b, ao, M_, D_, D_);
    // 6) x1 = LN(attn_out + x), + bf16 copy
    add_ln_kernel<1><<<dim3(M_), blk, 0, stream>>>(ao, x, ln1_g, ln1_b, x1, x1bf);
    // 7) h = gelu(x1 @ w1^T + b1) (MFMA, bf16 out)
    gemm_mfma<1, 1><<<dim3(FFN_ / 128, M_ / 128), blk, 0, stream>>>(x1bf, w1bf, b1, hbf, M_, FFN_, D_);
    // 8) y = h @ w2^T + b2 (MFMA, fp32 out)
    gemm_mfma<0, 0><<<dim3(D_ / 128, M_ / 128), blk, 0, stream>>>(hbf, w2bf, b2, ao, M_, D_, FFN_);
    // 9) out = LN(y + x1)
    add_ln_kernel<0><<<dim3(M_), blk, 0, stream>>>(ao, x1, ln2_g, ln2_b, out, nullptr);
}

// Round 4
// 163.080 us; speedup vs baseline: 4.2753x; 1.4298x over previous
//
#include <hip/hip_runtime.h>
#include <hip/hip_bf16.h>
#include <math.h>

#define B_   16
#define C_   512
#define D_   256
#define K_   16
#define RD_  128
#define H_   8
#define HD_  32
#define FFN_ 1024
#define M_   (B_ * C_)   // 8192 rows

typedef __attribute__((ext_vector_type(8))) short bf16x8;
typedef __attribute__((ext_vector_type(4))) float f32x4;

static __device__ __forceinline__ short f2bf(float v) {
    __hip_bfloat16 h = __float2bfloat16(v);
    return *(short*)&h;
}

// ---------------------------------------------------------------------------
// All fp32->bf16 conversions in ONE kernel. Segment boundaries compile-time.
// ---------------------------------------------------------------------------
#define N8_X    (M_ * D_ / 8)           // 262144
#define N8_INW  (768 * D_ / 8)          // 24576
#define N8_OUTW (D_ * D_ / 8)           // 8192
#define N8_W1   (FFN_ * D_ / 8)         // 32768
#define N8_W2   (D_ * FFN_ / 8)         // 32768
#define N8_TOT  (N8_X + N8_INW + N8_OUTW + N8_W1 + N8_W2)

__global__ __launch_bounds__(256) void convert_all_kernel(
    const float* __restrict__ x, const float* __restrict__ inw,
    const float* __restrict__ outw, const float* __restrict__ w1,
    const float* __restrict__ w2,
    short* __restrict__ xbf, short* __restrict__ inwbf,
    short* __restrict__ outwbf, short* __restrict__ w1bf,
    short* __restrict__ w2bf)
{
    int i = blockIdx.x * 256 + threadIdx.x;
    const float* s; short* d; int off;
    if      (i < N8_X)                          { s = x;    d = xbf;    off = i; }
    else if (i < N8_X + N8_INW)                 { s = inw;  d = inwbf;  off = i - N8_X; }
    else if (i < N8_X + N8_INW + N8_OUTW)       { s = outw; d = outwbf; off = i - N8_X - N8_INW; }
    else if (i < N8_X + N8_INW + N8_OUTW + N8_W1){ s = w1;  d = w1bf;   off = i - N8_X - N8_INW - N8_OUTW; }
    else if (i < N8_TOT)                        { s = w2;   d = w2bf;   off = i - N8_X - N8_INW - N8_OUTW - N8_W1; }
    else return;
    const float4* sp = (const float4*)s + (size_t)off * 2;
    float4 v0 = sp[0], v1 = sp[1];
    short r[8];
    r[0]=f2bf(v0.x); r[1]=f2bf(v0.y); r[2]=f2bf(v0.z); r[3]=f2bf(v0.w);
    r[4]=f2bf(v1.x); r[5]=f2bf(v1.y); r[6]=f2bf(v1.z); r[7]=f2bf(v1.w);
    *(bf16x8*)(d + (size_t)off * 8) = *(bf16x8*)r;
}

// ---------------------------------------------------------------------------
// bf16 MFMA GEMM: C[M,N] = A[M,Kd] @ W[N,Kd]^T + bias (+exact GELU).
// BM=128, BK=32, 256 threads = 4 waves.
// BN=128: waves 2x2, each 64x64 (4x4 frags).  BN=64: waves 4x1 (rows), each
// 32x64 (2x4 frags) -- doubles grid for small-N GEMMs.
// ---------------------------------------------------------------------------
template<int BN, int OUT_BF16, int ACT>
__global__ __launch_bounds__(256) void gemm_mfma(
    const short* __restrict__ A, const short* __restrict__ W,
    const float* __restrict__ bias, void* __restrict__ Cout,
    int M, int N, int Kd)
{
    __shared__ short As[128 * 32];
    __shared__ short Bs[BN * 32];
    const int tid  = threadIdx.x;
    const int wave = tid >> 6;
    const int lane = tid & 63;
    const int bm = blockIdx.y * 128;
    const int bn = blockIdx.x * BN;
    constexpr int MI = (BN == 128) ? 4 : 2;
    const int wr = (BN == 128) ? ((wave >> 1) * 64) : (wave * 32);
    const int wc = (BN == 128) ? ((wave & 1) * 64) : 0;

    const int fr = lane & 15;          // fragment row/col within 16
    const int fk = (lane >> 4) * 8;    // fragment k offset

    const int r0 = tid >> 2, ch = (tid & 3) * 8;
    const int r1 = r0 + 64;

    f32x4 acc[MI][4];
    #pragma unroll
    for (int i = 0; i < MI; ++i)
        #pragma unroll
        for (int j = 0; j < 4; ++j)
            acc[i][j] = (f32x4){0.f, 0.f, 0.f, 0.f};

    for (int k0 = 0; k0 < Kd; k0 += 32) {
        *(bf16x8*)&As[tid * 8]         = *(const bf16x8*)&A[(size_t)(bm + r0) * Kd + k0 + ch];
        *(bf16x8*)&As[(tid + 256) * 8] = *(const bf16x8*)&A[(size_t)(bm + r1) * Kd + k0 + ch];
        if constexpr (BN == 128) {
            *(bf16x8*)&Bs[tid * 8]         = *(const bf16x8*)&W[(size_t)(bn + r0) * Kd + k0 + ch];
            *(bf16x8*)&Bs[(tid + 256) * 8] = *(const bf16x8*)&W[(size_t)(bn + r1) * Kd + k0 + ch];
        } else {
            *(bf16x8*)&Bs[tid * 8]         = *(const bf16x8*)&W[(size_t)(bn + r0) * Kd + k0 + ch];
        }
        __syncthreads();
        bf16x8 af[MI], bfr[4];
        #pragma unroll
        for (int i = 0; i < MI; ++i) af[i]  = *(bf16x8*)&As[(wr + i * 16 + fr) * 32 + fk];
        #pragma unroll
        for (int j = 0; j < 4; ++j)  bfr[j] = *(bf16x8*)&Bs[(wc + j * 16 + fr) * 32 + fk];
        #pragma unroll
        for (int i = 0; i < MI; ++i)
            #pragma unroll
            for (int j = 0; j < 4; ++j)
                acc[i][j] = __builtin_amdgcn_mfma_f32_16x16x32_bf16(af[i], bfr[j], acc[i][j], 0, 0, 0);
        __syncthreads();
    }

    const int rowbase = (lane >> 4) * 4;
    #pragma unroll
    for (int i = 0; i < MI; ++i) {
        #pragma unroll
        for (int j = 0; j < 4; ++j) {
            const int n = bn + wc + j * 16 + fr;
            const float bn_v = bias ? bias[n] : 0.f;
            #pragma unroll
            for (int r = 0; r < 4; ++r) {
                const int m = bm + wr + i * 16 + rowbase + r;
                float v = acc[i][j][r] + bn_v;
                if (ACT) v = 0.5f * v * (1.0f + erff(v * 0.70710678118654752f));
                if (OUT_BF16) ((short*)Cout)[(size_t)m * N + n] = f2bf(v);
                else          ((float*)Cout)[(size_t)m * N + n] = v;
            }
        }
    }
}

// ---------------------------------------------------------------------------
// Fused xq/xk fp32 GEMM (exact, feeds top-k). blockIdx.z: 0 -> xq, 1 -> xk.
// 64x64 tile, BK=16, stride-68 LDS rows (16B-aligned -> ds_read_b128).
// ---------------------------------------------------------------------------
__global__ __launch_bounds__(256) void xqk_gemm(
    const float* __restrict__ x, const float* __restrict__ wq,
    const float* __restrict__ wk, float* __restrict__ xqo,
    float* __restrict__ xko)
{
    __shared__ float As[16 * 68];
    __shared__ float Ws[16 * 68];
    const float* Wm = blockIdx.z ? wk : wq;
    float* Cm       = blockIdx.z ? xko : xqo;

    const int tid = threadIdx.x;
    const int tx = tid & 15;
    const int ty = tid >> 4;
    const int bm = blockIdx.y * 64;
    const int bn = blockIdx.x * 64;

    float acc[4][4] = {};

    for (int k0 = 0; k0 < D_; k0 += 16) {
        #pragma unroll
        for (int i = 0; i < 4; ++i) {
            int e  = tid + i * 256;
            int r  = e >> 4;
            int kk = e & 15;
            As[kk * 68 + r] = x[(size_t)(bm + r) * D_ + k0 + kk];
            Ws[kk * 68 + r] = Wm[(size_t)(bn + r) * D_ + k0 + kk];
        }
        __syncthreads();
        #pragma unroll
        for (int kk = 0; kk < 16; ++kk) {
            float4 a = *(const float4*)&As[kk * 68 + ty * 4];
            float4 w = *(const float4*)&Ws[kk * 68 + tx * 4];
            float av[4] = {a.x, a.y, a.z, a.w};
            float wv[4] = {w.x, w.y, w.z, w.w};
            #pragma unroll
            for (int i = 0; i < 4; ++i)
                #pragma unroll
                for (int j = 0; j < 4; ++j)
                    acc[i][j] += av[i] * wv[j];
        }
        __syncthreads();
    }

    #pragma unroll
    for (int i = 0; i < 4; ++i)
        #pragma unroll
        for (int j = 0; j < 4; ++j)
            Cm[(size_t)(bm + ty * 4 + i) * RD_ + bn + tx * 4 + j] = acc[i][j];
}

// ---------------------------------------------------------------------------
// Batched logits GEMM (fp32, exact): logits[b,q,c] = xq[b,q,:] . xk[b,c,:]
// ---------------------------------------------------------------------------
__global__ __launch_bounds__(256) void logits_gemm(
    const float* __restrict__ xq, const float* __restrict__ xk,
    float* __restrict__ out)
{
    __shared__ float As[16 * 68];
    __shared__ float Ws[16 * 68];
    const int tid = threadIdx.x;
    const int tx = tid & 15;
    const int ty = tid >> 4;
    const int bm = blockIdx.y * 64;
    const int bn = blockIdx.x * 64;
    const int b  = blockIdx.z;

    const float* A = xq + (size_t)b * C_ * RD_;
    const float* W = xk + (size_t)b * C_ * RD_;
    float* Cmat    = out + (size_t)b * C_ * C_;

    float acc[4][4] = {};

    for (int k0 = 0; k0 < RD_; k0 += 16) {
        #pragma unroll
        for (int i = 0; i < 4; ++i) {
            int e  = tid + i * 256;
            int r  = e >> 4;
            int kk = e & 15;
            As[kk * 68 + r] = A[(size_t)(bm + r) * RD_ + k0 + kk];
            Ws[kk * 68 + r] = W[(size_t)(bn + r) * RD_ + k0 + kk];
        }
        __syncthreads();
        #pragma unroll
        for (int kk = 0; kk < 16; ++kk) {
            float4 a = *(const float4*)&As[kk * 68 + ty * 4];
            float4 w = *(const float4*)&Ws[kk * 68 + tx * 4];
            float av[4] = {a.x, a.y, a.z, a.w};
            float wv[4] = {w.x, w.y, w.z, w.w};
            #pragma unroll
            for (int i = 0; i < 4; ++i)
                #pragma unroll
                for (int j = 0; j < 4; ++j)
                    acc[i][j] += av[i] * wv[j];
        }
        __syncthreads();
    }

    #pragma unroll
    for (int i = 0; i < 4; ++i)
        #pragma unroll
        for (int j = 0; j < 4; ++j)
            Cmat[(size_t)(bm + ty * 4 + i) * C_ + bn + tx * 4 + j] = acc[i][j];
}

// ---------------------------------------------------------------------------
// Top-16 per 512-row, one wave per row, zero barriers.
// ---------------------------------------------------------------------------
__global__ __launch_bounds__(256) void topk_select(
    const float* __restrict__ logits, int* __restrict__ idx_out)
{
    const int wave = threadIdx.x >> 6;
    const int lane = threadIdx.x & 63;
    const int row  = blockIdx.x * 4 + wave;
    const float* lrow = logits + (size_t)row * C_;

    unsigned long long key[8];
    #pragma unroll
    for (int j = 0; j < 8; ++j) {
        int pos = lane * 8 + j;
        unsigned u = __float_as_uint(lrow[pos]);
        u = (u & 0x80000000u) ? ~u : (u | 0x80000000u);
        key[j] = (((unsigned long long)u) << 9) | (unsigned)(511 - pos);
    }

    #pragma unroll
    for (int sel = 0; sel < K_; ++sel) {
        unsigned long long best = key[0];
        #pragma unroll
        for (int j = 1; j < 8; ++j) best = key[j] > best ? key[j] : best;
        #pragma unroll
        for (int s = 1; s < 64; s <<= 1) {
            unsigned long long o = __shfl_xor(best, s, 64);
            best = o > best ? o : best;
        }
        int pos = 511 - (int)(best & 511ull);
        if (lane == 0) idx_out[(size_t)row * K_ + sel] = pos;
        if ((pos >> 3) == lane) key[pos & 7] = 0ull;
    }
}

// ---------------------------------------------------------------------------
// K=16 gathered attention, ONE WAVE per (b,q) row, zero barriers.
// Lane owns 4 dims (head = lane>>3). Scores via 8-lane xor-reduce; softmax
// fully in-register per lane. Writes bf16 ctx.
// ---------------------------------------------------------------------------
__global__ __launch_bounds__(256) void attn_wave_kernel(
    const float* __restrict__ qkv, const int* __restrict__ idx,
    short* __restrict__ ctxbf)
{
    const int wave = threadIdx.x >> 6;
    const int lane = threadIdx.x & 63;
    const int row  = blockIdx.x * 4 + wave;        // global (b*C + q)
    const int bbase = row & ~(C_ - 1);             // batch base row

    const float* qrow = qkv + (size_t)row * 768;
    float4 qv = *(const float4*)(qrow + lane * 4);

    int ii[K_];
    const int* ip = idx + (size_t)row * K_;
    #pragma unroll
    for (int k = 0; k < K_; ++k) ii[k] = ip[k];

    float s[K_];
    #pragma unroll
    for (int k = 0; k < K_; ++k) {
        const float* kr = qkv + (size_t)(bbase + ii[k]) * 768 + 256;
        float4 kv = *(const float4*)(kr + lane * 4);
        float p = qv.x * kv.x + qv.y * kv.y + qv.z * kv.z + qv.w * kv.w;
        p += __shfl_xor(p, 1, 64);
        p += __shfl_xor(p, 2, 64);
        p += __shfl_xor(p, 4, 64);
        s[k] = p * 0.17677669529663687f;
    }

    float m = s[0];
    #pragma unroll
    for (int k = 1; k < K_; ++k) m = fmaxf(m, s[k]);
    float ssum = 0.f;
    #pragma unroll
    for (int k = 0; k < K_; ++k) { s[k] = __expf(s[k] - m); ssum += s[k]; }
    const float inv = 1.f / ssum;

    float4 acc = {0.f, 0.f, 0.f, 0.f};
    #pragma unroll
    for (int k = 0; k < K_; ++k) {
        const float* vr = qkv + (size_t)(bbase + ii[k]) * 768 + 512;
        float4 vv = *(const float4*)(vr + lane * 4);
        float w = s[k] * inv;
        acc.x += w * vv.x; acc.y += w * vv.y; acc.z += w * vv.z; acc.w += w * vv.w;
    }

    unsigned lo = (unsigned)(unsigned short)f2bf(acc.x) | ((unsigned)(unsigned short)f2bf(acc.y) << 16);
    unsigned hi = (unsigned)(unsigned short)f2bf(acc.z) | ((unsigned)(unsigned short)f2bf(acc.w) << 16);
    uint2 pk = {lo, hi};
    *(uint2*)(ctxbf + (size_t)row * D_ + lane * 4) = pk;
}

// ---------------------------------------------------------------------------
// out = LN(a + res), ONE WAVE per row (shuffle reductions, no barriers).
// Optionally emits bf16 copy.
// ---------------------------------------------------------------------------
template<int WBF>
__global__ __launch_bounds__(256) void add_ln_wave_kernel(
    const float* __restrict__ a, const float* __restrict__ res,
    const float* __restrict__ g, const float* __restrict__ beta,
    float* __restrict__ out, short* __restrict__ outbf)
{
    const int wave = threadIdx.x >> 6;
    const int lane = threadIdx.x & 63;
    const int row  = blockIdx.x * 4 + wave;

    float4 va = *(const float4*)(a   + (size_t)row * D_ + lane * 4);
    float4 vr = *(const float4*)(res + (size_t)row * D_ + lane * 4);
    float4 v = {va.x + vr.x, va.y + vr.y, va.z + vr.z, va.w + vr.w};

    float t = v.x + v.y + v.z + v.w;
    #pragma unroll
    for (int s = 1; s < 64; s <<= 1) t += __shfl_xor(t, s, 64);
    const float mean = t * (1.0f / D_);

    float4 dv = {v.x - mean, v.y - mean, v.z - mean, v.w - mean};
    float sq = dv.x * dv.x + dv.y * dv.y + dv.z * dv.z + dv.w * dv.w;
    #pragma unroll
    for (int s = 1; s < 64; s <<= 1) sq += __shfl_xor(sq, s, 64);
    const float rstd = rsqrtf(sq * (1.0f / D_) + 1e-5f);

    float4 gv = *(const float4*)(g    + lane * 4);
    float4 bv = *(const float4*)(beta + lane * 4);
    float4 o = {dv.x * rstd * gv.x + bv.x, dv.y * rstd * gv.y + bv.y,
                dv.z * rstd * gv.z + bv.z, dv.w * rstd * gv.w + bv.w};
    *(float4*)(out + (size_t)row * D_ + lane * 4) = o;
    if (WBF) {
        unsigned lo = (unsigned)(unsigned short)f2bf(o.x) | ((unsigned)(unsigned short)f2bf(o.y) << 16);
        unsigned hi = (unsigned)(unsigned short)f2bf(o.z) | ((unsigned)(unsigned short)f2bf(o.w) << 16);
        uint2 pk = {lo, hi};
        *(uint2*)(outbf + (size_t)row * D_ + lane * 4) = pk;
    }
}

// ---------------------------------------------------------------------------
extern "C" void kernel_launch(void* const* d_in, const int* in_sizes, int n_in,
                              void* d_out, int out_size, void* d_ws, size_t ws_size,
                              hipStream_t stream)
{
    const float* x      = (const float*)d_in[0];
    const float* wq_rec = (const float*)d_in[1];
    const float* wk_rec = (const float*)d_in[2];
    const float* in_w   = (const float*)d_in[3];
    const float* in_b   = (const float*)d_in[4];
    const float* out_w  = (const float*)d_in[5];
    const float* out_b  = (const float*)d_in[6];
    const float* ln1_g  = (const float*)d_in[7];
    const float* ln1_b  = (const float*)d_in[8];
    const float* w1     = (const float*)d_in[9];
    const float* b1     = (const float*)d_in[10];
    const float* w2     = (const float*)d_in[11];
    const float* b2     = (const float*)d_in[12];
    const float* ln2_g  = (const float*)d_in[13];
    const float* ln2_b  = (const float*)d_in[14];
    float* out = (float*)d_out;

    // ---- workspace layout (floats) ----
    float* ws = (float*)d_ws;
    float* qkv   = ws;                              // M*768 f
    float* xq    = qkv + (size_t)M_ * 768;          // M*128 f
    float* xk    = xq  + (size_t)M_ * RD_;          // M*128 f
    int*   idx   = (int*)(xk + (size_t)M_ * RD_);   // M*16 i32
    float* x1    = (float*)(idx + (size_t)M_ * K_); // M*256 f
    float* ao    = x1 + (size_t)M_ * D_;            // M*256 f
    float* U     = ao + (size_t)M_ * D_;            // union region
    float* logits = U;                                  // M*512 f      (topk phase)
    short* ctxbf  = (short*)U;                          // M*256 bf16   (attn->outproj)
    short* x1bf   = (short*)U + (size_t)M_ * D_;        // M*256 bf16   (ln1->mlp1)
    short* hbf    = (short*)U + (size_t)2 * M_ * D_;    // M*1024 bf16  (mlp1->mlp2)
    float* afterU = U + (size_t)3 * M_ * D_;
    short* xbf    = (short*)afterU;                     // M*256 bf16
    short* inwbf  = xbf   + (size_t)M_ * D_;
    short* outwbf = inwbf + (size_t)768 * D_;
    short* w1bf   = outwbf + (size_t)D_ * D_;
    short* w2bf   = w1bf  + (size_t)FFN_ * D_;

    dim3 blk(256);

    // 0) all bf16 conversions, one launch
    convert_all_kernel<<<dim3((N8_TOT + 255) / 256), blk, 0, stream>>>(
        x, in_w, out_w, w1, w2, xbf, inwbf, outwbf, w1bf, w2bf);

    // 1) qkv = x @ in_proj_w^T + b  (MFMA)
    gemm_mfma<128, 0, 0><<<dim3(768 / 128, M_ / 128), blk, 0, stream>>>(xbf, inwbf, in_b, qkv, M_, 768, D_);
    // 2) xq/xk recurrence projections (fp32 exact), fused launch
    xqk_gemm<<<dim3(RD_ / 64, M_ / 64, 2), blk, 0, stream>>>(x, wq_rec, wk_rec, xq, xk);
    // 3) logits + top-16 (fp32 exact)
    logits_gemm<<<dim3(C_ / 64, C_ / 64, B_), blk, 0, stream>>>(xq, xk, logits);
    topk_select<<<dim3(M_ / 4), blk, 0, stream>>>(logits, idx);
    // 4) gathered attention -> ctx (bf16), wave-per-row
    attn_wave_kernel<<<dim3(M_ / 4), blk, 0, stream>>>(qkv, idx, ctxbf);
    // 5) out projection (MFMA, BN=64 -> 256 blocks)
    gemm_mfma<64, 0, 0><<<dim3(D_ / 64, M_ / 128), blk, 0, stream>>>(ctxbf, outwbf, out_b, ao, M_, D_, D_);
    // 6) x1 = LN(attn_out + x), + bf16 copy
    add_ln_wave_kernel<1><<<dim3(M_ / 4), blk, 0, stream>>>(ao, x, ln1_g, ln1_b, x1, x1bf);
    // 7) h = gelu(x1 @ w1^T + b1) (MFMA, bf16 out)
    gemm_mfma<128, 1, 1><<<dim3(FFN_ / 128, M_ / 128), blk, 0, stream>>>(x1bf, w1bf, b1, hbf, M_, FFN_, D_);
    // 8) y = h @ w2^T + b2 (MFMA, BN=64 -> 256 blocks)
    gemm_mfma<64, 0, 0><<<dim3(D_ / 64, M_ / 128), blk, 0, stream>>>(hbf, w2bf, b2, ao, M_, D_, FFN_);
    // 9) out = LN(y + x1)
    add_ln_wave_kernel<0><<<dim3(M_ / 4), blk, 0, stream>>>(ao, x1, ln2_g, ln2_b, out, nullptr);
}

// Round 5
// 144.708 us; speedup vs baseline: 4.8181x; 1.1270x over previous
//
#include <hip/hip_runtime.h>
#include <hip/hip_bf16.h>
#include <math.h>

#define B_   16
#define C_   512
#define D_   256
#define K_   16
#define RD_  128
#define H_   8
#define HD_  32
#define FFN_ 1024
#define M_   (B_ * C_)   // 8192 rows

typedef __attribute__((ext_vector_type(8))) short bf16x8;
typedef __attribute__((ext_vector_type(4))) float f32x4;

typedef __attribute__((address_space(1))) const int ga_int;
typedef __attribute__((address_space(3))) int ls_int;

static __device__ __forceinline__ short f2bf(float v) {
    __hip_bfloat16 h = __float2bfloat16(v);
    return *(short*)&h;
}

// ---------------------------------------------------------------------------
// All fp32->bf16 conversions in ONE kernel.
// ---------------------------------------------------------------------------
#define N8_X    (M_ * D_ / 8)
#define N8_INW  (768 * D_ / 8)
#define N8_OUTW (D_ * D_ / 8)
#define N8_W1   (FFN_ * D_ / 8)
#define N8_W2   (D_ * FFN_ / 8)
#define N8_TOT  (N8_X + N8_INW + N8_OUTW + N8_W1 + N8_W2)

__global__ __launch_bounds__(256) void convert_all_kernel(
    const float* __restrict__ x, const float* __restrict__ inw,
    const float* __restrict__ outw, const float* __restrict__ w1,
    const float* __restrict__ w2,
    short* __restrict__ xbf, short* __restrict__ inwbf,
    short* __restrict__ outwbf, short* __restrict__ w1bf,
    short* __restrict__ w2bf)
{
    int i = blockIdx.x * 256 + threadIdx.x;
    const float* s; short* d; int off;
    if      (i < N8_X)                          { s = x;    d = xbf;    off = i; }
    else if (i < N8_X + N8_INW)                 { s = inw;  d = inwbf;  off = i - N8_X; }
    else if (i < N8_X + N8_INW + N8_OUTW)       { s = outw; d = outwbf; off = i - N8_X - N8_INW; }
    else if (i < N8_X + N8_INW + N8_OUTW + N8_W1){ s = w1;  d = w1bf;   off = i - N8_X - N8_INW - N8_OUTW; }
    else if (i < N8_TOT)                        { s = w2;   d = w2bf;   off = i - N8_X - N8_INW - N8_OUTW - N8_W1; }
    else return;
    const float4* sp = (const float4*)s + (size_t)off * 2;
    float4 v0 = sp[0], v1 = sp[1];
    short r[8];
    r[0]=f2bf(v0.x); r[1]=f2bf(v0.y); r[2]=f2bf(v0.z); r[3]=f2bf(v0.w);
    r[4]=f2bf(v1.x); r[5]=f2bf(v1.y); r[6]=f2bf(v1.z); r[7]=f2bf(v1.w);
    *(bf16x8*)(d + (size_t)off * 8) = *(bf16x8*)r;
}

// ---------------------------------------------------------------------------
// bf16 MFMA GEMM: C[M,N] = A[M,Kd] @ W[N,Kd]^T + bias (+exact GELU).
// Template BM/BN; 256 threads = 4 waves in 2x2, each (BM/2)x(BN/2).
// Staging via global_load_lds (16B per lane, wave-uniform LDS base).
// ---------------------------------------------------------------------------
template<int BM, int BN, int OUT_BF16, int ACT>
__global__ __launch_bounds__(256) void gemm_mfma(
    const short* __restrict__ A, const short* __restrict__ W,
    const float* __restrict__ bias, void* __restrict__ Cout,
    int M, int N, int Kd)
{
    __shared__ short As[BM * 32];
    __shared__ short Bs[BN * 32];
    const int tid  = threadIdx.x;
    const int wave = tid >> 6;
    const int lane = tid & 63;
    const int bm = blockIdx.y * BM;
    const int bn = blockIdx.x * BN;
    constexpr int MI = BM / 32;
    constexpr int NJ = BN / 32;
    const int wr = (wave >> 1) * (BM / 2);
    const int wc = (wave & 1) * (BN / 2);

    const int fr = lane & 15;          // fragment row within 16
    const int fk = (lane >> 4) * 8;    // fragment k offset (shorts)

    const int r0 = tid >> 2, ch = (tid & 3) * 8;   // staging row / chunk

    f32x4 acc[MI][NJ];
    #pragma unroll
    for (int i = 0; i < MI; ++i)
        #pragma unroll
        for (int j = 0; j < NJ; ++j)
            acc[i][j] = (f32x4){0.f, 0.f, 0.f, 0.f};

    for (int k0 = 0; k0 < Kd; k0 += 32) {
        #pragma unroll
        for (int i = 0; i < BM / 64; ++i)
            __builtin_amdgcn_global_load_lds(
                (ga_int*)&A[(size_t)(bm + r0 + i * 64) * Kd + k0 + ch],
                (ls_int*)&As[(tid + i * 256) * 8], 16, 0, 0);
        #pragma unroll
        for (int j = 0; j < BN / 64; ++j)
            __builtin_amdgcn_global_load_lds(
                (ga_int*)&W[(size_t)(bn + r0 + j * 64) * Kd + k0 + ch],
                (ls_int*)&Bs[(tid + j * 256) * 8], 16, 0, 0);
        __syncthreads();

        bf16x8 af[MI], bfr[NJ];
        #pragma unroll
        for (int i = 0; i < MI; ++i) af[i]  = *(bf16x8*)&As[(wr + i * 16 + fr) * 32 + fk];
        #pragma unroll
        for (int j = 0; j < NJ; ++j) bfr[j] = *(bf16x8*)&Bs[(wc + j * 16 + fr) * 32 + fk];
        #pragma unroll
        for (int i = 0; i < MI; ++i)
            #pragma unroll
            for (int j = 0; j < NJ; ++j)
                acc[i][j] = __builtin_amdgcn_mfma_f32_16x16x32_bf16(af[i], bfr[j], acc[i][j], 0, 0, 0);
        __syncthreads();
    }

    const int rowbase = (lane >> 4) * 4;
    #pragma unroll
    for (int i = 0; i < MI; ++i) {
        #pragma unroll
        for (int j = 0; j < NJ; ++j) {
            const int n = bn + wc + j * 16 + fr;
            const float bn_v = bias ? bias[n] : 0.f;
            #pragma unroll
            for (int r = 0; r < 4; ++r) {
                const int m = bm + wr + i * 16 + rowbase + r;
                float v = acc[i][j][r] + bn_v;
                if (ACT) v = 0.5f * v * (1.0f + erff(v * 0.70710678118654752f));
                if (OUT_BF16) ((short*)Cout)[(size_t)m * N + n] = f2bf(v);
                else          ((float*)Cout)[(size_t)m * N + n] = v;
            }
        }
    }
}

// ---------------------------------------------------------------------------
// Fused xq/xk fp32 GEMM (exact, feeds top-k). blockIdx.z: 0 -> xq, 1 -> xk.
// ---------------------------------------------------------------------------
__global__ __launch_bounds__(256) void xqk_gemm(
    const float* __restrict__ x, const float* __restrict__ wq,
    const float* __restrict__ wk, float* __restrict__ xqo,
    float* __restrict__ xko)
{
    __shared__ float As[16 * 68];
    __shared__ float Ws[16 * 68];
    const float* Wm = blockIdx.z ? wk : wq;
    float* Cm       = blockIdx.z ? xko : xqo;

    const int tid = threadIdx.x;
    const int tx = tid & 15;
    const int ty = tid >> 4;
    const int bm = blockIdx.y * 64;
    const int bn = blockIdx.x * 64;

    float acc[4][4] = {};

    for (int k0 = 0; k0 < D_; k0 += 16) {
        #pragma unroll
        for (int i = 0; i < 4; ++i) {
            int e  = tid + i * 256;
            int r  = e >> 4;
            int kk = e & 15;
            As[kk * 68 + r] = x[(size_t)(bm + r) * D_ + k0 + kk];
            Ws[kk * 68 + r] = Wm[(size_t)(bn + r) * D_ + k0 + kk];
        }
        __syncthreads();
        #pragma unroll
        for (int kk = 0; kk < 16; ++kk) {
            float4 a = *(const float4*)&As[kk * 68 + ty * 4];
            float4 w = *(const float4*)&Ws[kk * 68 + tx * 4];
            float av[4] = {a.x, a.y, a.z, a.w};
            float wv[4] = {w.x, w.y, w.z, w.w};
            #pragma unroll
            for (int i = 0; i < 4; ++i)
                #pragma unroll
                for (int j = 0; j < 4; ++j)
                    acc[i][j] += av[i] * wv[j];
        }
        __syncthreads();
    }

    #pragma unroll
    for (int i = 0; i < 4; ++i)
        #pragma unroll
        for (int j = 0; j < 4; ++j)
            Cm[(size_t)(bm + ty * 4 + i) * RD_ + bn + tx * 4 + j] = acc[i][j];
}

// ---------------------------------------------------------------------------
// Batched logits GEMM (fp32, exact): logits[b,q,c] = xq[b,q,:] . xk[b,c,:]
// ---------------------------------------------------------------------------
__global__ __launch_bounds__(256) void logits_gemm(
    const float* __restrict__ xq, const float* __restrict__ xk,
    float* __restrict__ out)
{
    __shared__ float As[16 * 68];
    __shared__ float Ws[16 * 68];
    const int tid = threadIdx.x;
    const int tx = tid & 15;
    const int ty = tid >> 4;
    const int bm = blockIdx.y * 64;
    const int bn = blockIdx.x * 64;
    const int b  = blockIdx.z;

    const float* A = xq + (size_t)b * C_ * RD_;
    const float* W = xk + (size_t)b * C_ * RD_;
    float* Cmat    = out + (size_t)b * C_ * C_;

    float acc[4][4] = {};

    for (int k0 = 0; k0 < RD_; k0 += 16) {
        #pragma unroll
        for (int i = 0; i < 4; ++i) {
            int e  = tid + i * 256;
            int r  = e >> 4;
            int kk = e & 15;
            As[kk * 68 + r] = A[(size_t)(bm + r) * RD_ + k0 + kk];
            Ws[kk * 68 + r] = W[(size_t)(bn + r) * RD_ + k0 + kk];
        }
        __syncthreads();
        #pragma unroll
        for (int kk = 0; kk < 16; ++kk) {
            float4 a = *(const float4*)&As[kk * 68 + ty * 4];
            float4 w = *(const float4*)&Ws[kk * 68 + tx * 4];
            float av[4] = {a.x, a.y, a.z, a.w};
            float wv[4] = {w.x, w.y, w.z, w.w};
            #pragma unroll
            for (int i = 0; i < 4; ++i)
                #pragma unroll
                for (int j = 0; j < 4; ++j)
                    acc[i][j] += av[i] * wv[j];
        }
        __syncthreads();
    }

    #pragma unroll
    for (int i = 0; i < 4; ++i)
        #pragma unroll
        for (int j = 0; j < 4; ++j)
            Cmat[(size_t)(bm + ty * 4 + i) * C_ + bn + tx * 4 + j] = acc[i][j];
}

// ---------------------------------------------------------------------------
// FUSED top-16 + attention, ONE WAVE per (b,q) row, zero barriers.
// Top-k: order-preserving u64 keys, 16 rounds of reg-max + shuffle butterfly;
// winning pos is wave-uniform -> kept in registers, no idx buffer.
// Attention: lane owns 4 dims (head = lane>>3); 8-lane xor-reduce scores;
// softmax in-register; writes bf16 ctx.
// ---------------------------------------------------------------------------
__global__ __launch_bounds__(256) void topk_attn_kernel(
    const float* __restrict__ logits, const float* __restrict__ qkv,
    short* __restrict__ ctxbf)
{
    const int wave = threadIdx.x >> 6;
    const int lane = threadIdx.x & 63;
    const int row  = blockIdx.x * 4 + wave;        // global (b*C + q)
    const int bbase = row & ~(C_ - 1);             // batch base row

    // ---- top-16 ----
    const float* lrow = logits + (size_t)row * C_;
    unsigned long long key[8];
    #pragma unroll
    for (int j = 0; j < 8; ++j) {
        int pos = lane * 8 + j;
        unsigned u = __float_as_uint(lrow[pos]);
        u = (u & 0x80000000u) ? ~u : (u | 0x80000000u);
        key[j] = (((unsigned long long)u) << 9) | (unsigned)(511 - pos);
    }

    int ii[K_];
    #pragma unroll
    for (int sel = 0; sel < K_; ++sel) {
        unsigned long long best = key[0];
        #pragma unroll
        for (int j = 1; j < 8; ++j) best = key[j] > best ? key[j] : best;
        #pragma unroll
        for (int s = 1; s < 64; s <<= 1) {
            unsigned long long o = __shfl_xor(best, s, 64);
            best = o > best ? o : best;
        }
        int pos = 511 - (int)(best & 511ull);      // wave-uniform
        ii[sel] = pos;
        if ((pos >> 3) == lane) key[pos & 7] = 0ull;
    }

    // ---- attention over the 16 selected slots ----
    const float* qrow = qkv + (size_t)row * 768;
    float4 qv = *(const float4*)(qrow + lane * 4);

    float s[K_];
    #pragma unroll
    for (int k = 0; k < K_; ++k) {
        const float* kr = qkv + (size_t)(bbase + ii[k]) * 768 + 256;
        float4 kv = *(const float4*)(kr + lane * 4);
        float p = qv.x * kv.x + qv.y * kv.y + qv.z * kv.z + qv.w * kv.w;
        p += __shfl_xor(p, 1, 64);
        p += __shfl_xor(p, 2, 64);
        p += __shfl_xor(p, 4, 64);
        s[k] = p * 0.17677669529663687f;
    }

    float m = s[0];
    #pragma unroll
    for (int k = 1; k < K_; ++k) m = fmaxf(m, s[k]);
    float ssum = 0.f;
    #pragma unroll
    for (int k = 0; k < K_; ++k) { s[k] = __expf(s[k] - m); ssum += s[k]; }
    const float inv = 1.f / ssum;

    float4 acc = {0.f, 0.f, 0.f, 0.f};
    #pragma unroll
    for (int k = 0; k < K_; ++k) {
        const float* vr = qkv + (size_t)(bbase + ii[k]) * 768 + 512;
        float4 vv = *(const float4*)(vr + lane * 4);
        float w = s[k] * inv;
        acc.x += w * vv.x; acc.y += w * vv.y; acc.z += w * vv.z; acc.w += w * vv.w;
    }

    unsigned lo = (unsigned)(unsigned short)f2bf(acc.x) | ((unsigned)(unsigned short)f2bf(acc.y) << 16);
    unsigned hi = (unsigned)(unsigned short)f2bf(acc.z) | ((unsigned)(unsigned short)f2bf(acc.w) << 16);
    uint2 pk = {lo, hi};
    *(uint2*)(ctxbf + (size_t)row * D_ + lane * 4) = pk;
}

// ---------------------------------------------------------------------------
// out = LN(a + res), ONE WAVE per row (shuffle reductions, no barriers).
// ---------------------------------------------------------------------------
template<int WBF>
__global__ __launch_bounds__(256) void add_ln_wave_kernel(
    const float* __restrict__ a, const float* __restrict__ res,
    const float* __restrict__ g, const float* __restrict__ beta,
    float* __restrict__ out, short* __restrict__ outbf)
{
    const int wave = threadIdx.x >> 6;
    const int lane = threadIdx.x & 63;
    const int row  = blockIdx.x * 4 + wave;

    float4 va = *(const float4*)(a   + (size_t)row * D_ + lane * 4);
    float4 vr = *(const float4*)(res + (size_t)row * D_ + lane * 4);
    float4 v = {va.x + vr.x, va.y + vr.y, va.z + vr.z, va.w + vr.w};

    float t = v.x + v.y + v.z + v.w;
    #pragma unroll
    for (int s = 1; s < 64; s <<= 1) t += __shfl_xor(t, s, 64);
    const float mean = t * (1.0f / D_);

    float4 dv = {v.x - mean, v.y - mean, v.z - mean, v.w - mean};
    float sq = dv.x * dv.x + dv.y * dv.y + dv.z * dv.z + dv.w * dv.w;
    #pragma unroll
    for (int s = 1; s < 64; s <<= 1) sq += __shfl_xor(sq, s, 64);
    const float rstd = rsqrtf(sq * (1.0f / D_) + 1e-5f);

    float4 gv = *(const float4*)(g    + lane * 4);
    float4 bv = *(const float4*)(beta + lane * 4);
    float4 o = {dv.x * rstd * gv.x + bv.x, dv.y * rstd * gv.y + bv.y,
                dv.z * rstd * gv.z + bv.z, dv.w * rstd * gv.w + bv.w};
    *(float4*)(out + (size_t)row * D_ + lane * 4) = o;
    if (WBF) {
        unsigned lo = (unsigned)(unsigned short)f2bf(o.x) | ((unsigned)(unsigned short)f2bf(o.y) << 16);
        unsigned hi = (unsigned)(unsigned short)f2bf(o.z) | ((unsigned)(unsigned short)f2bf(o.w) << 16);
        uint2 pk = {lo, hi};
        *(uint2*)(outbf + (size_t)row * D_ + lane * 4) = pk;
    }
}

// ---------------------------------------------------------------------------
extern "C" void kernel_launch(void* const* d_in, const int* in_sizes, int n_in,
                              void* d_out, int out_size, void* d_ws, size_t ws_size,
                              hipStream_t stream)
{
    const float* x      = (const float*)d_in[0];
    const float* wq_rec = (const float*)d_in[1];
    const float* wk_rec = (const float*)d_in[2];
    const float* in_w   = (const float*)d_in[3];
    const float* in_b   = (const float*)d_in[4];
    const float* out_w  = (const float*)d_in[5];
    const float* out_b  = (const float*)d_in[6];
    const float* ln1_g  = (const float*)d_in[7];
    const float* ln1_b  = (const float*)d_in[8];
    const float* w1     = (const float*)d_in[9];
    const float* b1     = (const float*)d_in[10];
    const float* w2     = (const float*)d_in[11];
    const float* b2     = (const float*)d_in[12];
    const float* ln2_g  = (const float*)d_in[13];
    const float* ln2_b  = (const float*)d_in[14];
    float* out = (float*)d_out;

    // ---- workspace layout (floats) ----
    float* ws = (float*)d_ws;
    float* qkv   = ws;                              // M*768 f
    float* xq    = qkv + (size_t)M_ * 768;          // M*128 f
    float* xk    = xq  + (size_t)M_ * RD_;          // M*128 f
    float* x1    = xk  + (size_t)M_ * RD_;          // M*256 f
    float* ao    = x1 + (size_t)M_ * D_;            // M*256 f
    float* U     = ao + (size_t)M_ * D_;            // union region
    float* logits = U;                                  // M*512 f      (topk phase)
    short* ctxbf  = (short*)U;                          // M*256 bf16   (attn->outproj)
    short* x1bf   = (short*)U + (size_t)M_ * D_;        // M*256 bf16   (ln1->mlp1)
    short* hbf    = (short*)U + (size_t)2 * M_ * D_;    // M*1024 bf16  (mlp1->mlp2)
    float* afterU = U + (size_t)3 * M_ * D_;
    short* xbf    = (short*)afterU;                     // M*256 bf16
    short* inwbf  = xbf   + (size_t)M_ * D_;
    short* outwbf = inwbf + (size_t)768 * D_;
    short* w1bf   = outwbf + (size_t)D_ * D_;
    short* w2bf   = w1bf  + (size_t)FFN_ * D_;

    dim3 blk(256);

    // 0) all bf16 conversions, one launch
    convert_all_kernel<<<dim3((N8_TOT + 255) / 256), blk, 0, stream>>>(
        x, in_w, out_w, w1, w2, xbf, inwbf, outwbf, w1bf, w2bf);

    // 1) qkv = x @ in_proj_w^T + b  (MFMA, 64x128 -> 768 blocks)
    gemm_mfma<64, 128, 0, 0><<<dim3(768 / 128, M_ / 64), blk, 0, stream>>>(xbf, inwbf, in_b, qkv, M_, 768, D_);
    // 2) xq/xk recurrence projections (fp32 exact), fused launch
    xqk_gemm<<<dim3(RD_ / 64, M_ / 64, 2), blk, 0, stream>>>(x, wq_rec, wk_rec, xq, xk);
    // 3) logits (fp32 exact)
    logits_gemm<<<dim3(C_ / 64, C_ / 64, B_), blk, 0, stream>>>(xq, xk, logits);
    // 4) fused top-16 + gathered attention -> ctx (bf16)
    topk_attn_kernel<<<dim3(M_ / 4), blk, 0, stream>>>(logits, qkv, ctxbf);
    // 5) out projection (MFMA, 64x64 -> 512 blocks)
    gemm_mfma<64, 64, 0, 0><<<dim3(D_ / 64, M_ / 64), blk, 0, stream>>>(ctxbf, outwbf, out_b, ao, M_, D_, D_);
    // 6) x1 = LN(attn_out + x), + bf16 copy
    add_ln_wave_kernel<1><<<dim3(M_ / 4), blk, 0, stream>>>(ao, x, ln1_g, ln1_b, x1, x1bf);
    // 7) h = gelu(x1 @ w1^T + b1) (MFMA, 128x128 -> 512 blocks, bf16 out)
    gemm_mfma<128, 128, 1, 1><<<dim3(FFN_ / 128, M_ / 128), blk, 0, stream>>>(x1bf, w1bf, b1, hbf, M_, FFN_, D_);
    // 8) y = h @ w2^T + b2 (MFMA, 64x64 -> 512 blocks)
    gemm_mfma<64, 64, 0, 0><<<dim3(D_ / 64, M_ / 64), blk, 0, stream>>>(hbf, w2bf, b2, ao, M_, D_, FFN_);
    // 9) out = LN(y + x1)
    add_ln_wave_kernel<0><<<dim3(M_ / 4), blk, 0, stream>>>(ao, x1, ln2_g, ln2_b, out, nullptr);
}